// Round 5
// baseline (214.585 us; speedup 1.0000x reference)
//
#include <hip/hip_runtime.h>
#include <math.h>

// NeighborList: P = N*(N-1)/2 triu pairs, minimum-image distance, cutoff mask.
// out layout (float32, concatenated): [P] pair_i, [P] pair_j, [P*3] pair_diff, [P] pair_dist
//
// R5: per-row block mapping. Row index i = blockIdx.x, j = i+1+(p-off(i)) —
// no index arrays read from HBM, no f64 solve. xyz is padded to [N,4] in d_ws
// by a prep kernel so each j-side position is ONE aligned dwordx4 load; the
// i-side position is block-uniform (scalar loads). Full quads (global pair
// index p in [4*ceil(off/4), 4*floor((off+L)/4))) use float4 stores at the
// same global addresses as a flat mapping; <=3 head/tail pairs per row are
// stored scalar (dword-granular, so adjacent rows never collide).
// Reciprocal-mul min-image: rint flips only possible near |delta|~box/2 where
// the pair is masked under either image choice -> bit-identical outputs.

#define NL_CUTOFF 5.0f

typedef float f32x4 __attribute__((ext_vector_type(4)));

__global__ __launch_bounds__(256) void pad_xyz_kernel(
    const float* __restrict__ xyz, float* __restrict__ xyz4, int N)
{
    int a = blockIdx.x * blockDim.x + threadIdx.x;
    if (a < N) {
        f32x4 v = { xyz[3 * a + 0], xyz[3 * a + 1], xyz[3 * a + 2], 0.0f };
        ((f32x4*)xyz4)[a] = v;
    }
}

struct CellC {
    float r0x, r0y, r0z, rc0;   // row 0 and 1/cell[0][0]
    float r1x, r1y, r1z, rc1;   // row 1 and 1/cell[1][1]
    float r2x, r2y, r2z, rc2;   // row 2 and 1/cell[2][2]
};

__device__ __forceinline__ void pair_compute(
    float xi, float yi, float zi, float xj, float yj, float zj,
    const CellC& c, int ii, int jj,
    float& oi, float& oj, float& odx, float& ody, float& odz, float& orr)
{
    float dx = __fsub_rn(xi, xj);
    float dy = __fsub_rn(yi, yj);
    float dz = __fsub_rn(zi, zj);

    // z -> y -> x minimum image; reciprocal-mul is rint-safe (see header note)
    float s = rintf(__fmul_rn(dz, c.rc2));
    dx = __fsub_rn(dx, __fmul_rn(s, c.r2x));
    dy = __fsub_rn(dy, __fmul_rn(s, c.r2y));
    dz = __fsub_rn(dz, __fmul_rn(s, c.r2z));

    s = rintf(__fmul_rn(dy, c.rc1));
    dx = __fsub_rn(dx, __fmul_rn(s, c.r1x));
    dy = __fsub_rn(dy, __fmul_rn(s, c.r1y));
    dz = __fsub_rn(dz, __fmul_rn(s, c.r1z));

    s = rintf(__fmul_rn(dx, c.rc0));
    dx = __fsub_rn(dx, __fmul_rn(s, c.r0x));
    dy = __fsub_rn(dy, __fmul_rn(s, c.r0y));
    dz = __fsub_rn(dz, __fmul_rn(s, c.r0z));

    float ss = __fadd_rn(__fadd_rn(__fmul_rn(dx, dx), __fmul_rn(dy, dy)),
                         __fmul_rn(dz, dz));
    float r = __fsqrt_rn(ss);      // correctly rounded: mask boundary bit-exact
    bool m = (r < NL_CUTOFF);

    oi  = m ? (float)ii : -1.0f;
    oj  = m ? (float)jj : -1.0f;
    odx = m ? dx : 0.0f;
    ody = m ? dy : 0.0f;
    odz = m ? dz : 0.0f;
    orr = m ? r  : 0.0f;
}

__global__ __launch_bounds__(256) void nl_row_kernel(
    const float* __restrict__ xyz4,
    const float* __restrict__ cell,
    float* __restrict__ out,
    long long P, int N)
{
    CellC c;
    c.r0x = cell[0]; c.r0y = cell[1]; c.r0z = cell[2];
    c.r1x = cell[3]; c.r1y = cell[4]; c.r1z = cell[5];
    c.r2x = cell[6]; c.r2y = cell[7]; c.r2z = cell[8];
    c.rc0 = __fdiv_rn(1.0f, c.r0x);
    c.rc1 = __fdiv_rn(1.0f, c.r1y);
    c.rc2 = __fdiv_rn(1.0f, c.r2z);

    const int       i   = blockIdx.x;                       // row, 0..N-2
    const long long L   = (long long)(N - 1 - i);           // pairs in row
    const long long off = ((long long)i * (2LL * N - 1 - i)) >> 1;

    const f32x4 pi = ((const f32x4*)xyz4)[i];               // block-uniform
    const float xi = pi.x, yi = pi.y, zi = pi.z;

    float* __restrict__ out_i = out;
    float* __restrict__ out_j = out + P;
    float* __restrict__ out_d = out + 2 * P;   // [P,3] row-major
    float* __restrict__ out_r = out + 5 * P;

    long long qstart = (off + 3) >> 2;          // ceil(off/4)
    long long qend   = (off + L) >> 2;          // floor((off+L)/4)
    long long fq_lo, fq_hi;
    if (qend > qstart) { fq_lo = qstart << 2; fq_hi = qend << 2; }
    else { fq_lo = off; fq_hi = off; qstart = 0; qend = 0; }   // no full quads

    // full quads: float4 stores at flat global addresses
    for (long long q = qstart + threadIdx.x; q < qend; q += blockDim.x) {
        const long long p  = q << 2;
        const int       j0 = i + 1 + (int)(p - off);

        const f32x4 pj0 = ((const f32x4*)xyz4)[j0 + 0];
        const f32x4 pj1 = ((const f32x4*)xyz4)[j0 + 1];
        const f32x4 pj2 = ((const f32x4*)xyz4)[j0 + 2];
        const f32x4 pj3 = ((const f32x4*)xyz4)[j0 + 3];

        float oia[4], oja[4], ora[4], od[12];
        pair_compute(xi, yi, zi, pj0.x, pj0.y, pj0.z, c, i, j0 + 0,
                     oia[0], oja[0], od[0], od[1], od[2], ora[0]);
        pair_compute(xi, yi, zi, pj1.x, pj1.y, pj1.z, c, i, j0 + 1,
                     oia[1], oja[1], od[3], od[4], od[5], ora[1]);
        pair_compute(xi, yi, zi, pj2.x, pj2.y, pj2.z, c, i, j0 + 2,
                     oia[2], oja[2], od[6], od[7], od[8], ora[2]);
        pair_compute(xi, yi, zi, pj3.x, pj3.y, pj3.z, c, i, j0 + 3,
                     oia[3], oja[3], od[9], od[10], od[11], ora[3]);

        ((float4*)out_i)[q] = make_float4(oia[0], oia[1], oia[2], oia[3]);
        ((float4*)out_j)[q] = make_float4(oja[0], oja[1], oja[2], oja[3]);
        ((float4*)out_r)[q] = make_float4(ora[0], ora[1], ora[2], ora[3]);
        float4* dd = (float4*)(out_d + 12 * q);
        dd[0] = make_float4(od[0], od[1],  od[2],  od[3]);
        dd[1] = make_float4(od[4], od[5],  od[6],  od[7]);
        dd[2] = make_float4(od[8], od[9],  od[10], od[11]);
    }

    // edge pairs: [off, fq_lo) and [fq_hi, off+L), <=3 each (whole row if tiny)
    const long long ne1 = fq_lo - off;
    const long long ne2 = (off + L) - fq_hi;
    const long long t   = threadIdx.x;
    long long p = -1;
    if (t < ne1)            p = off + t;
    else if (t < ne1 + ne2) p = fq_hi + (t - ne1);
    if (p >= 0) {
        const int j = i + 1 + (int)(p - off);
        const f32x4 pj = ((const f32x4*)xyz4)[j];
        float oi, oj, dx, dy, dz, rr;
        pair_compute(xi, yi, zi, pj.x, pj.y, pj.z, c, i, j,
                     oi, oj, dx, dy, dz, rr);
        out_i[p] = oi;
        out_j[p] = oj;
        out_d[3 * p + 0] = dx;
        out_d[3 * p + 1] = dy;
        out_d[3 * p + 2] = dz;
        out_r[p] = rr;
    }
}

extern "C" void kernel_launch(void* const* d_in, const int* in_sizes, int n_in,
                              void* d_out, int out_size, void* d_ws, size_t ws_size,
                              hipStream_t stream) {
    const float* xyz  = (const float*)d_in[0];
    const float* cell = (const float*)d_in[1];
    float* out  = (float*)d_out;
    float* xyz4 = (float*)d_ws;     // [N,4] padded positions, 16*N bytes

    const int       N = in_sizes[0] / 3;
    const long long P = (long long)in_sizes[2];

    pad_xyz_kernel<<<(N + 255) / 256, 256, 0, stream>>>(xyz, xyz4, N);
    nl_row_kernel<<<N - 1, 256, 0, stream>>>(xyz4, cell, out, P, N);
}

// Round 6
// 170.449 us; speedup vs baseline: 1.2589x; 1.2589x over previous
//
#include <hip/hip_runtime.h>
#include <math.h>

// NeighborList: P = N*(N-1)/2 triu pairs, minimum-image distance, cutoff mask.
// out layout (float32, concatenated): [P] pair_i, [P] pair_j, [P*3] pair_diff, [P] pair_dist
//
// R6 = R4 schedule (2048-block flat grid-stride over quads, analytic triu
// index solve per quad) + SoA coordinates in d_ws (xs/ys/zs), so the j-side
// gather is one coalesced dwordx4 per coordinate instead of 12 strided dword
// loads (R4's exposed L1 cost). i-side is quad-uniform broadcast. Rare quads
// that cross a row boundary (~1/1024) take a scalar fallback walk.
// Reciprocal-mul min-image: rint flips only possible near |delta|~box/2 where
// the pair is masked under either image choice -> bit-identical outputs.

#define NL_CUTOFF 5.0f

typedef float f32x4  __attribute__((ext_vector_type(4)));
typedef float f32x4u __attribute__((ext_vector_type(4), aligned(4)));  // 4B-aligned vec load

// i,j from linear triu pair index p: row i starts at off(i) = i*(2N-1-i)/2.
__device__ __forceinline__ void solve_ij(long long p, int N, int& io, int& jo) {
    const double A = (double)(2 * N - 1);
    double disc = A * A - 8.0 * (double)p;
    long long ii = (long long)((A - sqrt(disc)) * 0.5);
    if (ii < 0) ii = 0;
    if (ii > N - 2) ii = N - 2;
    // exact integer fixup (f64 sqrt rounding can be off by 1)
    while (ii > 0 && (ii * (2LL * N - 1 - ii)) >> 1 > p) --ii;
    while (((ii + 1) * (2LL * N - 1 - (ii + 1))) >> 1 <= p) ++ii;
    const long long off = (ii * (2LL * N - 1 - ii)) >> 1;
    io = (int)ii;
    jo = (int)(p - off + ii + 1);
}

__global__ __launch_bounds__(256) void soa_kernel(
    const float* __restrict__ xyz,
    float* __restrict__ xs, float* __restrict__ ys, float* __restrict__ zs, int N)
{
    int a = blockIdx.x * blockDim.x + threadIdx.x;
    if (a < N) {
        xs[a] = xyz[3 * a + 0];
        ys[a] = xyz[3 * a + 1];
        zs[a] = xyz[3 * a + 2];
    }
}

struct CellC {
    float r0x, r0y, r0z, rc0;   // row 0 and 1/cell[0][0]
    float r1x, r1y, r1z, rc1;   // row 1 and 1/cell[1][1]
    float r2x, r2y, r2z, rc2;   // row 2 and 1/cell[2][2]
};

__device__ __forceinline__ void pair_compute(
    float xi, float yi, float zi, float xj, float yj, float zj,
    const CellC& c, int ii, int jj,
    float& oi, float& oj, float& odx, float& ody, float& odz, float& orr)
{
    float dx = __fsub_rn(xi, xj);
    float dy = __fsub_rn(yi, yj);
    float dz = __fsub_rn(zi, zj);

    // z -> y -> x minimum image; reciprocal-mul is rint-safe (see header note)
    float s = rintf(__fmul_rn(dz, c.rc2));
    dx = __fsub_rn(dx, __fmul_rn(s, c.r2x));
    dy = __fsub_rn(dy, __fmul_rn(s, c.r2y));
    dz = __fsub_rn(dz, __fmul_rn(s, c.r2z));

    s = rintf(__fmul_rn(dy, c.rc1));
    dx = __fsub_rn(dx, __fmul_rn(s, c.r1x));
    dy = __fsub_rn(dy, __fmul_rn(s, c.r1y));
    dz = __fsub_rn(dz, __fmul_rn(s, c.r1z));

    s = rintf(__fmul_rn(dx, c.rc0));
    dx = __fsub_rn(dx, __fmul_rn(s, c.r0x));
    dy = __fsub_rn(dy, __fmul_rn(s, c.r0y));
    dz = __fsub_rn(dz, __fmul_rn(s, c.r0z));

    float ss = __fadd_rn(__fadd_rn(__fmul_rn(dx, dx), __fmul_rn(dy, dy)),
                         __fmul_rn(dz, dz));
    float r = __fsqrt_rn(ss);      // correctly rounded: mask boundary bit-exact
    bool m = (r < NL_CUTOFF);

    oi  = m ? (float)ii : -1.0f;
    oj  = m ? (float)jj : -1.0f;
    odx = m ? dx : 0.0f;
    ody = m ? dy : 0.0f;
    odz = m ? dz : 0.0f;
    orr = m ? r  : 0.0f;
}

__global__ __launch_bounds__(256) void nl_kernel(
    const float* __restrict__ xs,
    const float* __restrict__ ys,
    const float* __restrict__ zs,
    const float* __restrict__ cell,
    float* __restrict__ out,
    long long P, int N)
{
    CellC c;
    c.r0x = cell[0]; c.r0y = cell[1]; c.r0z = cell[2];
    c.r1x = cell[3]; c.r1y = cell[4]; c.r1z = cell[5];
    c.r2x = cell[6]; c.r2y = cell[7]; c.r2z = cell[8];
    c.rc0 = __fdiv_rn(1.0f, c.r0x);
    c.rc1 = __fdiv_rn(1.0f, c.r1y);
    c.rc2 = __fdiv_rn(1.0f, c.r2z);

    float* __restrict__ out_i = out;
    float* __restrict__ out_j = out + P;
    float* __restrict__ out_d = out + 2 * P;   // [P,3] row-major
    float* __restrict__ out_r = out + 5 * P;

    const long long nquad  = P >> 2;
    const long long stride = (long long)gridDim.x * blockDim.x;
    const long long tid0   = (long long)blockIdx.x * blockDim.x + threadIdx.x;

    for (long long q = tid0; q < nquad; q += stride) {
        int i, j;
        solve_ij(q << 2, N, i, j);

        float oia[4], oja[4], ora[4], od[12];
        if (j + 3 <= N - 1) {
            // fast path: all 4 pairs in row i, consecutive j — coalesced x4 loads
            const float xi = xs[i], yi = ys[i], zi = zs[i];
            const f32x4u jx = *(const f32x4u*)(xs + j);
            const f32x4u jy = *(const f32x4u*)(ys + j);
            const f32x4u jz = *(const f32x4u*)(zs + j);
#pragma unroll
            for (int k = 0; k < 4; ++k) {
                pair_compute(xi, yi, zi, jx[k], jy[k], jz[k], c, i, j + k,
                             oia[k], oja[k], od[3 * k + 0], od[3 * k + 1],
                             od[3 * k + 2], ora[k]);
            }
        } else {
            // slow path: quad crosses row boundary (~1/1024 of quads)
            int ii = i, jj = j;
#pragma unroll
            for (int k = 0; k < 4; ++k) {
                pair_compute(xs[ii], ys[ii], zs[ii], xs[jj], ys[jj], zs[jj],
                             c, ii, jj,
                             oia[k], oja[k], od[3 * k + 0], od[3 * k + 1],
                             od[3 * k + 2], ora[k]);
                if (++jj >= N) { ++ii; jj = ii + 1; }
            }
        }

        ((float4*)out_i)[q] = make_float4(oia[0], oia[1], oia[2], oia[3]);
        ((float4*)out_j)[q] = make_float4(oja[0], oja[1], oja[2], oja[3]);
        ((float4*)out_r)[q] = make_float4(ora[0], ora[1], ora[2], ora[3]);
        float4* dd = (float4*)(out_d + 12 * q);
        dd[0] = make_float4(od[0], od[1],  od[2],  od[3]);
        dd[1] = make_float4(od[4], od[5],  od[6],  od[7]);
        dd[2] = make_float4(od[8], od[9],  od[10], od[11]);
    }

    // tail (P % 4 != 0 safety; P is divisible by 4 for N=8192)
    for (long long p = (nquad << 2) + tid0; p < P; p += stride) {
        int i, j;
        solve_ij(p, N, i, j);
        float oi, oj, dx, dy, dz, rr;
        pair_compute(xs[i], ys[i], zs[i], xs[j], ys[j], zs[j], c, i, j,
                     oi, oj, dx, dy, dz, rr);
        out_i[p] = oi;
        out_j[p] = oj;
        out_d[3 * p + 0] = dx;
        out_d[3 * p + 1] = dy;
        out_d[3 * p + 2] = dz;
        out_r[p] = rr;
    }
}

extern "C" void kernel_launch(void* const* d_in, const int* in_sizes, int n_in,
                              void* d_out, int out_size, void* d_ws, size_t ws_size,
                              hipStream_t stream) {
    const float* xyz  = (const float*)d_in[0];
    const float* cell = (const float*)d_in[1];
    float* out = (float*)d_out;

    const int       N = in_sizes[0] / 3;
    const long long P = (long long)in_sizes[2];

    float* xs = (float*)d_ws;       // [N]
    float* ys = xs + N;             // [N]
    float* zs = ys + N;             // [N]

    soa_kernel<<<(N + 255) / 256, 256, 0, stream>>>(xyz, xs, ys, zs, N);

    const int block = 256;
    long long nquad = P >> 2;
    long long blocks_needed = (nquad + block - 1) / block;
    int grid = (int)(blocks_needed < 2048 ? (blocks_needed > 0 ? blocks_needed : 1)
                                          : 2048);

    nl_kernel<<<grid, block, 0, stream>>>(xs, ys, zs, cell, out, P, N);
}

// Round 7
// 165.726 us; speedup vs baseline: 1.2948x; 1.0285x over previous
//
#include <hip/hip_runtime.h>
#include <math.h>

// NeighborList: P = N*(N-1)/2 triu pairs, minimum-image distance, cutoff mask.
// out layout (float32, concatenated): [P] pair_i, [P] pair_j, [P*3] pair_diff, [P] pair_dist
//
// R7 = R4 structure (single kernel, 2048-block grid-stride over quads, scalar
// xyz gathers — R6 proved loads are cache-absorbed) with VALU cut:
//  - diagonal-cell fast path (wave-uniform runtime check): cross terms are
//    d - s*0 == d bit-exactly in f32, so skipping them is bit-identical.
//  - solve_ij in pure int32 + f32 sqrt: disc = A^2-8p is exact in int32,
//    f32 sqrt gives ii within ~1e-3 and the integer fixup loops (32-bit
//    muls) guarantee exactness. No f64 anywhere.
// Reciprocal-mul min-image: rint flips only possible near |delta|~box/2 where
// the pair is masked under either image choice -> bit-identical outputs.

#define NL_CUTOFF 5.0f

// i,j from linear triu pair index p (int32 domain: P < 2^31).
// off(i) = i*(A-i)/2 with A = 2N-1; products < 2^31.
__device__ __forceinline__ void solve_ij(int p, int N, int& io, int& jo) {
    const int A = 2 * N - 1;
    const int disc = A * A - 8 * p;                 // exact, >= 9
    const float sd = __fsqrt_rn((float)disc);
    int ii = (int)(__fmul_rn(__fsub_rn((float)A, sd), 0.5f));
    if (ii < 0) ii = 0;
    if (ii > N - 2) ii = N - 2;
    while (ii > 0 && ((ii * (A - ii)) >> 1) > p) --ii;
    while ((((ii + 1) * (A - ii - 1)) >> 1) <= p) ++ii;
    io = ii;
    jo = p - ((ii * (A - ii)) >> 1) + ii + 1;
}

struct CellC {
    float r0x, r0y, r0z, rc0;   // row 0 and 1/cell[0][0]
    float r1x, r1y, r1z, rc1;   // row 1 and 1/cell[1][1]
    float r2x, r2y, r2z, rc2;   // row 2 and 1/cell[2][2]
};

template <bool DIAG>
__device__ __forceinline__ void pair_compute(
    float xi, float yi, float zi, float xj, float yj, float zj,
    const CellC& c, float fi, float fj,
    float& oi, float& oj, float& odx, float& ody, float& odz, float& orr)
{
    float dx = __fsub_rn(xi, xj);
    float dy = __fsub_rn(yi, yj);
    float dz = __fsub_rn(zi, zj);

    if (DIAG) {
        // diagonal cell: off-axis updates are d - s*0 == d bit-exactly
        float s = rintf(__fmul_rn(dz, c.rc2));
        dz = __fsub_rn(dz, __fmul_rn(s, c.r2z));
        s = rintf(__fmul_rn(dy, c.rc1));
        dy = __fsub_rn(dy, __fmul_rn(s, c.r1y));
        s = rintf(__fmul_rn(dx, c.rc0));
        dx = __fsub_rn(dx, __fmul_rn(s, c.r0x));
    } else {
        float s = rintf(__fmul_rn(dz, c.rc2));
        dx = __fsub_rn(dx, __fmul_rn(s, c.r2x));
        dy = __fsub_rn(dy, __fmul_rn(s, c.r2y));
        dz = __fsub_rn(dz, __fmul_rn(s, c.r2z));

        s = rintf(__fmul_rn(dy, c.rc1));
        dx = __fsub_rn(dx, __fmul_rn(s, c.r1x));
        dy = __fsub_rn(dy, __fmul_rn(s, c.r1y));
        dz = __fsub_rn(dz, __fmul_rn(s, c.r1z));

        s = rintf(__fmul_rn(dx, c.rc0));
        dx = __fsub_rn(dx, __fmul_rn(s, c.r0x));
        dy = __fsub_rn(dy, __fmul_rn(s, c.r0y));
        dz = __fsub_rn(dz, __fmul_rn(s, c.r0z));
    }

    float ss = __fadd_rn(__fadd_rn(__fmul_rn(dx, dx), __fmul_rn(dy, dy)),
                         __fmul_rn(dz, dz));
    float r = __fsqrt_rn(ss);      // correctly rounded: mask boundary bit-exact
    bool m = (r < NL_CUTOFF);

    oi  = m ? fi : -1.0f;
    oj  = m ? fj : -1.0f;
    odx = m ? dx : 0.0f;
    ody = m ? dy : 0.0f;
    odz = m ? dz : 0.0f;
    orr = m ? r  : 0.0f;
}

template <bool DIAG>
__device__ __forceinline__ void nl_body(
    const float* __restrict__ xyz, const CellC& c,
    float* __restrict__ out, long long P, int N)
{
    float* __restrict__ out_i = out;
    float* __restrict__ out_j = out + P;
    float* __restrict__ out_d = out + 2 * P;   // [P,3] row-major
    float* __restrict__ out_r = out + 5 * P;

    const long long nquad  = P >> 2;
    const long long stride = (long long)gridDim.x * blockDim.x;
    const long long tid0   = (long long)blockIdx.x * blockDim.x + threadIdx.x;

    for (long long q = tid0; q < nquad; q += stride) {
        int i, j;
        solve_ij((int)(q << 2), N, i, j);

        float oia[4], oja[4], ora[4], od[12];
        if (j + 3 <= N - 1) {
            // all 4 pairs in row i, consecutive j
            const float xi = xyz[3 * i + 0], yi = xyz[3 * i + 1], zi = xyz[3 * i + 2];
            const float fi = (float)i, fj = (float)j;
#pragma unroll
            for (int k = 0; k < 4; ++k) {
                pair_compute<DIAG>(xi, yi, zi,
                                   xyz[3 * (j + k) + 0], xyz[3 * (j + k) + 1],
                                   xyz[3 * (j + k) + 2],
                                   c, fi, fj + (float)k,
                                   oia[k], oja[k], od[3 * k + 0], od[3 * k + 1],
                                   od[3 * k + 2], ora[k]);
            }
        } else {
            // quad crosses a row boundary (~1/1024 of quads)
            int ii = i, jj = j;
#pragma unroll
            for (int k = 0; k < 4; ++k) {
                pair_compute<DIAG>(xyz[3 * ii + 0], xyz[3 * ii + 1], xyz[3 * ii + 2],
                                   xyz[3 * jj + 0], xyz[3 * jj + 1], xyz[3 * jj + 2],
                                   c, (float)ii, (float)jj,
                                   oia[k], oja[k], od[3 * k + 0], od[3 * k + 1],
                                   od[3 * k + 2], ora[k]);
                if (++jj >= N) { ++ii; jj = ii + 1; }
            }
        }

        ((float4*)out_i)[q] = make_float4(oia[0], oia[1], oia[2], oia[3]);
        ((float4*)out_j)[q] = make_float4(oja[0], oja[1], oja[2], oja[3]);
        ((float4*)out_r)[q] = make_float4(ora[0], ora[1], ora[2], ora[3]);
        float4* dd = (float4*)(out_d + 12 * q);
        dd[0] = make_float4(od[0], od[1],  od[2],  od[3]);
        dd[1] = make_float4(od[4], od[5],  od[6],  od[7]);
        dd[2] = make_float4(od[8], od[9],  od[10], od[11]);
    }

    // tail (P % 4 != 0 safety; P divisible by 4 for N=8192)
    for (long long p = (nquad << 2) + tid0; p < P; p += stride) {
        int i, j;
        solve_ij((int)p, N, i, j);
        float oi, oj, dx, dy, dz, rr;
        pair_compute<DIAG>(xyz[3 * i + 0], xyz[3 * i + 1], xyz[3 * i + 2],
                           xyz[3 * j + 0], xyz[3 * j + 1], xyz[3 * j + 2],
                           c, (float)i, (float)j, oi, oj, dx, dy, dz, rr);
        out_i[p] = oi;
        out_j[p] = oj;
        out_d[3 * p + 0] = dx;
        out_d[3 * p + 1] = dy;
        out_d[3 * p + 2] = dz;
        out_r[p] = rr;
    }
}

__global__ __launch_bounds__(256) void nl_kernel(
    const float* __restrict__ xyz,
    const float* __restrict__ cell,
    float* __restrict__ out,
    long long P, int N)
{
    CellC c;
    c.r0x = cell[0]; c.r0y = cell[1]; c.r0z = cell[2];
    c.r1x = cell[3]; c.r1y = cell[4]; c.r1z = cell[5];
    c.r2x = cell[6]; c.r2y = cell[7]; c.r2z = cell[8];
    c.rc0 = __fdiv_rn(1.0f, c.r0x);
    c.rc1 = __fdiv_rn(1.0f, c.r1y);
    c.rc2 = __fdiv_rn(1.0f, c.r2z);

    const bool diag = (c.r0y == 0.0f) && (c.r0z == 0.0f) &&
                      (c.r1x == 0.0f) && (c.r1z == 0.0f) &&
                      (c.r2x == 0.0f) && (c.r2y == 0.0f);

    if (diag) nl_body<true>(xyz, c, out, P, N);
    else      nl_body<false>(xyz, c, out, P, N);
}

extern "C" void kernel_launch(void* const* d_in, const int* in_sizes, int n_in,
                              void* d_out, int out_size, void* d_ws, size_t ws_size,
                              hipStream_t stream) {
    const float* xyz  = (const float*)d_in[0];
    const float* cell = (const float*)d_in[1];
    float* out = (float*)d_out;

    const int       N = in_sizes[0] / 3;
    const long long P = (long long)in_sizes[2];

    const int block = 256;
    long long nquad = P >> 2;
    long long blocks_needed = (nquad + block - 1) / block;
    int grid = (int)(blocks_needed < 2048 ? (blocks_needed > 0 ? blocks_needed : 1)
                                          : 2048);

    nl_kernel<<<grid, block, 0, stream>>>(xyz, cell, out, P, N);
}

// Round 8
// 156.546 us; speedup vs baseline: 1.3707x; 1.0586x over previous
//
#include <hip/hip_runtime.h>
#include <math.h>

// NeighborList: P = N*(N-1)/2 triu pairs, minimum-image distance, cutoff mask.
// out layout (float32, concatenated): [P] pair_i, [P] pair_j, [P*3] pair_diff, [P] pair_dist
//
// R8 = R7 + per-wave LDS transpose of the pair_diff stream so ALL global
// stores are lane-contiguous 16-lines-per-instruction (the diff stream was
// 3 float4 stores at 48B lane stride = 48 partial lines/instr; R3's
// nontemporal regression proved partial-line write handling is expensive).
// Intra-wave exchange only (per-wave LDS slab, no __syncthreads needed);
// rotation swizzle slot = 3*lane + (m+lane)%3 keeps LDS conflicts <=3-way.
// Reciprocal-mul min-image + diag fast path: bit-identical (see notes below).

#define NL_CUTOFF 5.0f

typedef float f32x4 __attribute__((ext_vector_type(4)));

// i,j from linear triu pair index p (int32 domain: P < 2^31).
__device__ __forceinline__ void solve_ij(int p, int N, int& io, int& jo) {
    const int A = 2 * N - 1;
    const int disc = A * A - 8 * p;                 // exact, >= 9
    const float sd = __fsqrt_rn((float)disc);
    int ii = (int)(__fmul_rn(__fsub_rn((float)A, sd), 0.5f));
    if (ii < 0) ii = 0;
    if (ii > N - 2) ii = N - 2;
    while (ii > 0 && ((ii * (A - ii)) >> 1) > p) --ii;
    while ((((ii + 1) * (A - ii - 1)) >> 1) <= p) ++ii;
    io = ii;
    jo = p - ((ii * (A - ii)) >> 1) + ii + 1;
}

struct CellC {
    float r0x, r0y, r0z, rc0;
    float r1x, r1y, r1z, rc1;
    float r2x, r2y, r2z, rc2;
};

template <bool DIAG>
__device__ __forceinline__ void pair_compute(
    float xi, float yi, float zi, float xj, float yj, float zj,
    const CellC& c, float fi, float fj,
    float& oi, float& oj, float& odx, float& ody, float& odz, float& orr)
{
    float dx = __fsub_rn(xi, xj);
    float dy = __fsub_rn(yi, yj);
    float dz = __fsub_rn(zi, zj);

    if (DIAG) {
        // diagonal cell: off-axis updates are d - s*0 == d bit-exactly
        float s = rintf(__fmul_rn(dz, c.rc2));
        dz = __fsub_rn(dz, __fmul_rn(s, c.r2z));
        s = rintf(__fmul_rn(dy, c.rc1));
        dy = __fsub_rn(dy, __fmul_rn(s, c.r1y));
        s = rintf(__fmul_rn(dx, c.rc0));
        dx = __fsub_rn(dx, __fmul_rn(s, c.r0x));
    } else {
        float s = rintf(__fmul_rn(dz, c.rc2));
        dx = __fsub_rn(dx, __fmul_rn(s, c.r2x));
        dy = __fsub_rn(dy, __fmul_rn(s, c.r2y));
        dz = __fsub_rn(dz, __fmul_rn(s, c.r2z));

        s = rintf(__fmul_rn(dy, c.rc1));
        dx = __fsub_rn(dx, __fmul_rn(s, c.r1x));
        dy = __fsub_rn(dy, __fmul_rn(s, c.r1y));
        dz = __fsub_rn(dz, __fmul_rn(s, c.r1z));

        s = rintf(__fmul_rn(dx, c.rc0));
        dx = __fsub_rn(dx, __fmul_rn(s, c.r0x));
        dy = __fsub_rn(dy, __fmul_rn(s, c.r0y));
        dz = __fsub_rn(dz, __fmul_rn(s, c.r0z));
    }

    float ss = __fadd_rn(__fadd_rn(__fmul_rn(dx, dx), __fmul_rn(dy, dy)),
                         __fmul_rn(dz, dz));
    float r = __fsqrt_rn(ss);      // correctly rounded: mask boundary bit-exact
    bool m = (r < NL_CUTOFF);

    oi  = m ? fi : -1.0f;
    oj  = m ? fj : -1.0f;
    odx = m ? dx : 0.0f;
    ody = m ? dy : 0.0f;
    odz = m ? dz : 0.0f;
    orr = m ? r  : 0.0f;
}

template <bool DIAG>
__device__ __forceinline__ void nl_body(
    const float* __restrict__ xyz, const CellC& c,
    float* __restrict__ out, long long P, int N,
    f32x4* __restrict__ wslab)          // per-wave 192-float4 LDS slab
{
    float* __restrict__ out_i = out;
    float* __restrict__ out_j = out + P;
    float* __restrict__ out_d = out + 2 * P;   // [P,3] row-major
    float* __restrict__ out_r = out + 5 * P;

    const long long nquad  = P >> 2;
    const long long stride = (long long)gridDim.x * blockDim.x;
    const long long tid0   = (long long)blockIdx.x * blockDim.x + threadIdx.x;
    const int       lane   = (int)(threadIdx.x & 63);
    const int       lm     = lane % 3;

    for (long long q = tid0; q < nquad; q += stride) {
        int i, j;
        solve_ij((int)(q << 2), N, i, j);

        float oia[4], oja[4], ora[4], od[12];
        if (j + 3 <= N - 1) {
            const float xi = xyz[3 * i + 0], yi = xyz[3 * i + 1], zi = xyz[3 * i + 2];
            const float fi = (float)i, fj = (float)j;
#pragma unroll
            for (int k = 0; k < 4; ++k) {
                pair_compute<DIAG>(xi, yi, zi,
                                   xyz[3 * (j + k) + 0], xyz[3 * (j + k) + 1],
                                   xyz[3 * (j + k) + 2],
                                   c, fi, fj + (float)k,
                                   oia[k], oja[k], od[3 * k + 0], od[3 * k + 1],
                                   od[3 * k + 2], ora[k]);
            }
        } else {
            int ii = i, jj = j;
#pragma unroll
            for (int k = 0; k < 4; ++k) {
                pair_compute<DIAG>(xyz[3 * ii + 0], xyz[3 * ii + 1], xyz[3 * ii + 2],
                                   xyz[3 * jj + 0], xyz[3 * jj + 1], xyz[3 * jj + 2],
                                   c, (float)ii, (float)jj,
                                   oia[k], oja[k], od[3 * k + 0], od[3 * k + 1],
                                   od[3 * k + 2], ora[k]);
                if (++jj >= N) { ++ii; jj = ii + 1; }
            }
        }

        ((float4*)out_i)[q] = make_float4(oia[0], oia[1], oia[2], oia[3]);
        ((float4*)out_j)[q] = make_float4(oja[0], oja[1], oja[2], oja[3]);
        ((float4*)out_r)[q] = make_float4(ora[0], ora[1], ora[2], ora[3]);

        const f32x4 pd0 = {od[0], od[1], od[2],  od[3]};
        const f32x4 pd1 = {od[4], od[5], od[6],  od[7]};
        const f32x4 pd2 = {od[8], od[9], od[10], od[11]};

        const long long qw = q - lane;              // wave-uniform base quad
        if (qw + 63 < nquad) {
            // wave fully active: LDS transpose -> lane-contiguous dd stores.
            // write slot = 3*lane + (m+lane)%3 (rotation keeps conflicts <=3-way)
            int s0 = lm;
            int s1 = lm + 1; if (s1 >= 3) s1 -= 3;
            int s2 = lm + 2; if (s2 >= 3) s2 -= 3;
            wslab[3 * lane + s0] = pd0;
            wslab[3 * lane + s1] = pd1;
            wslab[3 * lane + s2] = pd2;
            __builtin_amdgcn_wave_barrier();
            f32x4* __restrict__ dd4 = (f32x4*)out_d;   // 16B-aligned (P%4==0)
#pragma unroll
            for (int m = 0; m < 3; ++m) {
                const int f  = m * 64 + lane;          // flat float4 idx in wave tile
                const int r  = f / 3;                  // owner lane
                const int cc = f - 3 * r;              // component
                int s = cc + r % 3; if (s >= 3) s -= 3;
                const f32x4 v = wslab[3 * r + s];
                dd4[3 * qw + f] = v;                   // contiguous 1KB/instr
            }
            __builtin_amdgcn_wave_barrier();
        } else {
            float4* dd = (float4*)(out_d + 12 * q);
            dd[0] = make_float4(od[0], od[1],  od[2],  od[3]);
            dd[1] = make_float4(od[4], od[5],  od[6],  od[7]);
            dd[2] = make_float4(od[8], od[9],  od[10], od[11]);
        }
    }

    // tail (P % 4 != 0 safety; P divisible by 4 for N=8192)
    for (long long p = (nquad << 2) + tid0; p < P; p += stride) {
        int i, j;
        solve_ij((int)p, N, i, j);
        float oi, oj, dx, dy, dz, rr;
        pair_compute<DIAG>(xyz[3 * i + 0], xyz[3 * i + 1], xyz[3 * i + 2],
                           xyz[3 * j + 0], xyz[3 * j + 1], xyz[3 * j + 2],
                           c, (float)i, (float)j, oi, oj, dx, dy, dz, rr);
        out_i[p] = oi;
        out_j[p] = oj;
        out_d[3 * p + 0] = dx;
        out_d[3 * p + 1] = dy;
        out_d[3 * p + 2] = dz;
        out_r[p] = rr;
    }
}

__global__ __launch_bounds__(256) void nl_kernel(
    const float* __restrict__ xyz,
    const float* __restrict__ cell,
    float* __restrict__ out,
    long long P, int N)
{
    __shared__ f32x4 slab[4][192];     // one 3KB slab per wave (block = 4 waves)

    CellC c;
    c.r0x = cell[0]; c.r0y = cell[1]; c.r0z = cell[2];
    c.r1x = cell[3]; c.r1y = cell[4]; c.r1z = cell[5];
    c.r2x = cell[6]; c.r2y = cell[7]; c.r2z = cell[8];
    c.rc0 = __fdiv_rn(1.0f, c.r0x);
    c.rc1 = __fdiv_rn(1.0f, c.r1y);
    c.rc2 = __fdiv_rn(1.0f, c.r2z);

    const bool diag = (c.r0y == 0.0f) && (c.r0z == 0.0f) &&
                      (c.r1x == 0.0f) && (c.r1z == 0.0f) &&
                      (c.r2x == 0.0f) && (c.r2y == 0.0f);

    const int wid = threadIdx.x >> 6;
    if (diag) nl_body<true>(xyz, c, out, P, N, slab[wid]);
    else      nl_body<false>(xyz, c, out, P, N, slab[wid]);
}

extern "C" void kernel_launch(void* const* d_in, const int* in_sizes, int n_in,
                              void* d_out, int out_size, void* d_ws, size_t ws_size,
                              hipStream_t stream) {
    const float* xyz  = (const float*)d_in[0];
    const float* cell = (const float*)d_in[1];
    float* out = (float*)d_out;

    const int       N = in_sizes[0] / 3;
    const long long P = (long long)in_sizes[2];

    const int block = 256;
    long long nquad = P >> 2;
    long long blocks_needed = (nquad + block - 1) / block;
    int grid = (int)(blocks_needed < 2048 ? (blocks_needed > 0 ? blocks_needed : 1)
                                          : 2048);

    nl_kernel<<<grid, block, 0, stream>>>(xyz, cell, out, P, N);
}